// Round 6
// baseline (51.576 us; speedup 1.0000x reference)
//
#include <hip/hip_runtime.h>
#include <hip/hip_bf16.h>

// Shapes: keypoints (8,5,2) f32, mesh_grid (1024,2) f32, W (10,512) f32,
// distance_matrix (1024,1024) i32 in [0,64). Output (8,8,1024,1024) f32.
//
// Reshape semantics: A (B,N,512) -> (B,8,N,64) row-major raw reshape:
//   n_orig = h*128 + (n_new>>3);  o = (n_new&7)*64 + k
// out[b,h,n,m] = A_new[b,h,n, dm[n,m]]
//
// R5 = R4 with PLAIN stores (A/B: drop nontemporal so L2 write-combining
// aggregates the 1 KB wave stores into full-line HBM bursts, like the
// 6.9 TB/s fill kernel). Everything else identical: one wave = one
// contiguous 4 KB output row; table in one register (k = lane); gather via
// ds_bpermute (conflict-free); blockIdx n-fast for fill-like streams.

#define NN 1024

typedef float f32x4 __attribute__((ext_vector_type(4)));

__global__ __launch_bounds__(256) void KR_RPE_10582799417497_kernel(
    const float* __restrict__ kp,    // (8,5,2)
    const float* __restrict__ mesh,  // (1024,2)
    const float* __restrict__ W,     // (10,512)
    const int*   __restrict__ dm,    // (1024,1024)
    float* __restrict__ out)         // (8,8,1024,1024)
{
    const int bid  = blockIdx.x;
    const int g    = bid >> 10;       // plane group 0..15 (slow)
    const int n    = bid & (NN - 1);  // row 0..1023 (fast)
    const int t    = threadIdx.x;
    const int lane = t & 63;
    const int w    = t >> 6;          // wave 0..3
    const int bh   = g * 4 + w;       // this wave's output plane
    const int b    = bh >> 3, h = bh & 7;

    const int n0 = n >> 3;            // n_orig = h*128 + n0
    const int oo = (n & 7) * 64;      // o base
    const int k  = lane;              // this lane's table column

    // W column slice for k (coalesced 256 B per load)
    float Wv[10];
#pragma unroll
    for (int f = 0; f < 10; ++f) Wv[f] = W[f * 512 + oo + k];

    // one-register gather table: A[bh][k = lane]
    const int n_orig = h * 128 + n0;
    const float mx = mesh[n_orig * 2 + 0];
    const float my = mesh[n_orig * 2 + 1];
    float acc = 0.f;
#pragma unroll
    for (int p = 0; p < 5; ++p) {
        acc += (mx - kp[b * 10 + p * 2 + 0]) * Wv[p * 2 + 0]
             + (my - kp[b * 10 + p * 2 + 1]) * Wv[p * 2 + 1];
    }
    const int s = __float_as_int(acc);

    const int* dr = dm + (size_t)n * NN;              // shared by all 4 waves (L1)
    float* op = out + ((size_t)bh * NN + n) * NN;     // this wave's 4 KB row

#pragma unroll
    for (int it = 0; it < 4; ++it) {
        const int4 kk = *(const int4*)(dr + it * 256 + lane * 4);
        f32x4 v;
        v.x = __int_as_float(__builtin_amdgcn_ds_bpermute(kk.x * 4, s));
        v.y = __int_as_float(__builtin_amdgcn_ds_bpermute(kk.y * 4, s));
        v.z = __int_as_float(__builtin_amdgcn_ds_bpermute(kk.z * 4, s));
        v.w = __int_as_float(__builtin_amdgcn_ds_bpermute(kk.w * 4, s));
        *(f32x4*)(op + it * 256 + lane * 4) = v;
    }
}

extern "C" void kernel_launch(void* const* d_in, const int* in_sizes, int n_in,
                              void* d_out, int out_size, void* d_ws, size_t ws_size,
                              hipStream_t stream) {
    const float* kp   = (const float*)d_in[0];
    const float* mesh = (const float*)d_in[1];
    const float* W    = (const float*)d_in[2];
    const int*   dm   = (const int*)d_in[3];
    float* out = (float*)d_out;

    KR_RPE_10582799417497_kernel<<<16 * NN, 256, 0, stream>>>(kp, mesh, W, dm, out);
}